// Round 3
// baseline (317.324 us; speedup 1.0000x reference)
//
#include <hip/hip_runtime.h>
#include <cstdint>
#include <cstddef>

#define BATCH 4096
#define F_FOLLOW 50
#define NROW 51            // 1 + F
#define DU 128
#define DI 256
#define DT 768
#define K1 (DT + DI)       // 1024
#define K2 (DU + DI)       // 384
#define EPS 1e-5f

// ---------------------------------------------------------------------------
// Attention over [u, followed...] rows. One block (256 thr) per batch row.
// Only gathers rows 0..follow_len (rows beyond have softmax weight 0: the
// reference masks them to -1e9 and exp(-1e9 - m) underflows to exactly 0).
// Block 0 additionally zeroes the 768-float BN accumulator region.
// ---------------------------------------------------------------------------
__global__ __launch_bounds__(256) void attn_kernel(
    const int* __restrict__ user_id,
    const int* __restrict__ user_follow,
    const int* __restrict__ follow_len,
    const float* __restrict__ utab,     // [NU,128]
    float* __restrict__ uemb_out,       // [B,128]
    float* __restrict__ zero_region)    // [768] BN sum/sumsq accumulators
{
    __shared__ float uf[NROW * 133];    // stride 133: conflict-free reads
    __shared__ int   idx[NROW];
    __shared__ float w[NROW];

    const int b   = blockIdx.x;
    const int tid = threadIdx.x;

    if (b == 0)
        for (int i = tid; i < 768; i += 256) zero_region[i] = 0.f;

    const int fl  = follow_len[b];
    const int nv  = fl < F_FOLLOW ? fl : F_FOLLOW;   // last valid row index

    if (tid < NROW)
        idx[tid] = (tid == 0) ? user_id[b] : user_follow[b * F_FOLLOW + tid - 1];
    __syncthreads();

    const int nrows = nv + 1;
    for (int e = tid; e < nrows * 32; e += 256) {
        int n = e >> 5, d4 = (e & 31) << 2;
        float4 v = *(const float4*)(utab + (size_t)idx[n] * 128 + d4);
        float* dst = &uf[n * 133 + d4];
        dst[0] = v.x; dst[1] = v.y; dst[2] = v.z; dst[3] = v.w;
    }
    __syncthreads();

    if (tid < 64) {
        int n = (tid <= nv) ? tid : 0;
        float acc = 0.f;
        #pragma unroll 8
        for (int d = 0; d < 128; ++d)
            acc += uf[n * 133 + d] * uf[d];          // uf[d] == u[d], broadcast
        float s = (tid <= nv) ? acc : -1e30f;
        float m = s;
        #pragma unroll
        for (int off = 32; off; off >>= 1)
            m = fmaxf(m, __shfl_xor(m, off, 64));
        float e = expf(s - m);
        float l = e;
        #pragma unroll
        for (int off = 32; off; off >>= 1)
            l += __shfl_xor(l, off, 64);
        if (tid < NROW) w[tid] = e / l;
    }
    __syncthreads();

    if (tid < 128) {
        float acc = 0.f;
        for (int n = 0; n <= nv; ++n)
            acc += w[n] * uf[n * 133 + tid];
        float out = (fl > 1) ? acc : uf[tid];
        uemb_out[(size_t)b * DU + tid] = out;
    }
}

// ---------------------------------------------------------------------------
// GEMM1: a1 = [tag | item_emb] @ w1^T + b1 + item_emb   (fp32, 64x64 tile,
// BK=32, 512 threads). Fused per-column sum/sumsq for BN1.
// ---------------------------------------------------------------------------
__global__ __launch_bounds__(512) void gemm1_kernel(
    const float* __restrict__ tag,      // [B,768]
    const int*   __restrict__ item_id,
    const float* __restrict__ itab,     // [NI,256]
    const float* __restrict__ w1,       // [256,1024]
    const float* __restrict__ b1,       // [256]
    float* __restrict__ a1,             // [B,256]
    float* __restrict__ gsum,           // [256]
    float* __restrict__ gsq)            // [256]
{
    __shared__ float As[32][68];
    __shared__ float Bs[32][68];
    __shared__ int   iid[64];
    __shared__ float lsum[64];
    __shared__ float lsq[64];

    const int tid = threadIdx.x;
    const int m0 = blockIdx.x * 64;
    const int n0 = blockIdx.y * 64;
    if (tid < 64) {
        iid[tid]  = item_id[m0 + tid];
        lsum[tid] = 0.f;
        lsq[tid]  = 0.f;
    }

    const int lr = tid >> 3;           // 0..63 : row (A) / out-col (B)
    const int lk = (tid & 7) * 4;      // 0,4,...,28
    const int tx = tid & 15;           // 16 col-groups of 4
    const int ty = tid >> 4;           // 0..31 row-groups of 2

    float acc[2][4] = {};
    __syncthreads();

    for (int kt = 0; kt < K1; kt += 32) {
        float4 av, bv;
        if (kt < DT)
            av = *(const float4*)(tag + (size_t)(m0 + lr) * DT + kt + lk);
        else
            av = *(const float4*)(itab + (size_t)iid[lr] * DI + (kt - DT) + lk);
        bv = *(const float4*)(w1 + (size_t)(n0 + lr) * K1 + kt + lk);

        __syncthreads();
        As[lk + 0][lr] = av.x; As[lk + 1][lr] = av.y;
        As[lk + 2][lr] = av.z; As[lk + 3][lr] = av.w;
        Bs[lk + 0][lr] = bv.x; Bs[lk + 1][lr] = bv.y;
        Bs[lk + 2][lr] = bv.z; Bs[lk + 3][lr] = bv.w;
        __syncthreads();

        #pragma unroll
        for (int k = 0; k < 32; ++k) {
            float2 a2v = *(const float2*)&As[k][ty * 2];
            float4 b4  = *(const float4*)&Bs[k][tx * 4];
            float a[2]  = {a2v.x, a2v.y};
            float bb[4] = {b4.x, b4.y, b4.z, b4.w};
            #pragma unroll
            for (int i = 0; i < 2; ++i)
                #pragma unroll
                for (int j = 0; j < 4; ++j)
                    acc[i][j] += a[i] * bb[j];
        }
    }

    float s[4] = {0.f, 0.f, 0.f, 0.f};
    float q[4] = {0.f, 0.f, 0.f, 0.f};
    #pragma unroll
    for (int i = 0; i < 2; ++i) {
        int lrow = ty * 2 + i;
        int row  = m0 + lrow;
        int ii   = iid[lrow];
        #pragma unroll
        for (int j = 0; j < 4; ++j) {
            int col = n0 + tx * 4 + j;
            float v = acc[i][j] + b1[col] + itab[(size_t)ii * DI + col];
            a1[(size_t)row * DI + col] = v;
            s[j] += v;
            q[j] += v * v;
        }
    }
    #pragma unroll
    for (int j = 0; j < 4; ++j) {
        atomicAdd(&lsum[tx * 4 + j], s[j]);
        atomicAdd(&lsq [tx * 4 + j], q[j]);
    }
    __syncthreads();
    if (tid < 64) {
        atomicAdd(&gsum[n0 + tid], lsum[tid]);
        atomicAdd(&gsq [n0 + tid], lsq [tid]);
    }
}

// ---------------------------------------------------------------------------
// GEMM2: a2 = [uemb | relu(bn1(a1))] @ w2^T + b2 + uemb  (32x64 tile, BK=32).
// BN1 scale/shift computed in-block from global sums (bnprep folded in);
// BN1 apply fused into A-tile load; fused per-column sum/sumsq for BN2.
// ---------------------------------------------------------------------------
__global__ __launch_bounds__(256) void gemm2_kernel(
    const float* __restrict__ uemb,    // [B,128]
    const float* __restrict__ a1,      // [B,256]
    const float* __restrict__ gsum1,   // [256]
    const float* __restrict__ gsq1,    // [256]
    const float* __restrict__ g1,      // [256]
    const float* __restrict__ bb1,     // [256]
    const float* __restrict__ w2,      // [128,384]
    const float* __restrict__ b2,      // [128]
    float* __restrict__ a2,            // [B,128]
    float* __restrict__ gsum,          // [128]
    float* __restrict__ gsq)           // [128]
{
    __shared__ float As[32][36];
    __shared__ float Bs[32][68];
    __shared__ __align__(16) float sc1s[256];
    __shared__ __align__(16) float sh1s[256];
    __shared__ float lsum[64];
    __shared__ float lsq[64];

    const int tid = threadIdx.x;
    const int m0 = blockIdx.x * 32;
    const int n0 = blockIdx.y * 64;

    {   // folded bnprep1: one column per thread
        float mean = gsum1[tid] * (1.f / 4096.f);
        float var  = gsq1[tid] * (1.f / 4096.f) - mean * mean;
        var = fmaxf(var, 0.f);
        float sc = g1[tid] / sqrtf(var + EPS);
        sc1s[tid] = sc;
        sh1s[tid] = bb1[tid] - mean * sc;
    }
    if (tid < 64) { lsum[tid] = 0.f; lsq[tid] = 0.f; }

    const int ar = tid >> 3;            // 0..31
    const int ak = (tid & 7) * 4;       // 0,4,...,28
    const int br = tid >> 2;            // 0..63
    const int bk = (tid & 3) * 8;       // 0,8,16,24
    const int tx = tid & 15;
    const int ty = tid >> 4;

    float acc[2][4] = {};
    __syncthreads();

    for (int kt = 0; kt < K2; kt += 32) {
        float4 av;
        int row = m0 + ar;
        if (kt < DU) {
            av = *(const float4*)(uemb + (size_t)row * DU + kt + ak);
        } else {
            int c = kt + ak - DU;
            float4 v  = *(const float4*)(a1 + (size_t)row * DI + c);
            float4 sv = *(const float4*)(sc1s + c);
            float4 hv = *(const float4*)(sh1s + c);
            av.x = fmaxf(v.x * sv.x + hv.x, 0.f);
            av.y = fmaxf(v.y * sv.y + hv.y, 0.f);
            av.z = fmaxf(v.z * sv.z + hv.z, 0.f);
            av.w = fmaxf(v.w * sv.w + hv.w, 0.f);
        }
        const float* wrow = w2 + (size_t)(n0 + br) * K2 + kt + bk;
        float4 bv0 = *(const float4*)(wrow);
        float4 bv1 = *(const float4*)(wrow + 4);

        __syncthreads();
        As[ak + 0][ar] = av.x; As[ak + 1][ar] = av.y;
        As[ak + 2][ar] = av.z; As[ak + 3][ar] = av.w;
        Bs[bk + 0][br] = bv0.x; Bs[bk + 1][br] = bv0.y;
        Bs[bk + 2][br] = bv0.z; Bs[bk + 3][br] = bv0.w;
        Bs[bk + 4][br] = bv1.x; Bs[bk + 5][br] = bv1.y;
        Bs[bk + 6][br] = bv1.z; Bs[bk + 7][br] = bv1.w;
        __syncthreads();

        #pragma unroll
        for (int k = 0; k < 32; ++k) {
            float2 a2v = *(const float2*)&As[k][ty * 2];
            float4 b4  = *(const float4*)&Bs[k][tx * 4];
            float a[2]  = {a2v.x, a2v.y};
            float bb[4] = {b4.x, b4.y, b4.z, b4.w};
            #pragma unroll
            for (int i = 0; i < 2; ++i)
                #pragma unroll
                for (int j = 0; j < 4; ++j)
                    acc[i][j] += a[i] * bb[j];
        }
    }

    float s[4] = {0.f, 0.f, 0.f, 0.f};
    float q[4] = {0.f, 0.f, 0.f, 0.f};
    #pragma unroll
    for (int i = 0; i < 2; ++i) {
        int row = m0 + ty * 2 + i;
        #pragma unroll
        for (int j = 0; j < 4; ++j) {
            int col = n0 + tx * 4 + j;
            float v = acc[i][j] + b2[col] + uemb[(size_t)row * DU + col];
            a2[(size_t)row * DU + col] = v;
            s[j] += v;
            q[j] += v * v;
        }
    }
    #pragma unroll
    for (int j = 0; j < 4; ++j) {
        atomicAdd(&lsum[tx * 4 + j], s[j]);
        atomicAdd(&lsq [tx * 4 + j], q[j]);
    }
    __syncthreads();
    if (tid < 64) {
        atomicAdd(&gsum[n0 + tid], lsum[tid]);
        atomicAdd(&gsq [n0 + tid], lsq [tid]);
    }
}

// ---------------------------------------------------------------------------
// Final: logits = [relu(bn2(a2)) | feat] @ out_w^T + out_b. One wave per row.
// BN2 scale/shift computed in-block from global sums (bnprep folded in).
// ---------------------------------------------------------------------------
__global__ __launch_bounds__(256) void final_kernel(
    const float* __restrict__ a2,
    const float* __restrict__ gsum2,   // [128]
    const float* __restrict__ gsq2,    // [128]
    const float* __restrict__ g2,      // [128]
    const float* __restrict__ bb2,     // [128]
    const float* __restrict__ feat,
    const float* __restrict__ ow, const float* __restrict__ ob,
    float* __restrict__ out)
{
    __shared__ float sc2s[128];
    __shared__ float sh2s[128];

    const int tid  = threadIdx.x;
    if (tid < 128) {
        float mean = gsum2[tid] * (1.f / 4096.f);
        float var  = gsq2[tid] * (1.f / 4096.f) - mean * mean;
        var = fmaxf(var, 0.f);
        float sc = g2[tid] / sqrtf(var + EPS);
        sc2s[tid] = sc;
        sh2s[tid] = bb2[tid] - mean * sc;
    }
    __syncthreads();

    const int lane = tid & 63;
    const int wv   = tid >> 6;
    const int b    = blockIdx.x * 4 + wv;

    float acc = 0.f;
    #pragma unroll
    for (int h = 0; h < 2; ++h) {
        int j = lane + h * 64;
        float v = fmaxf(a2[(size_t)b * DU + j] * sc2s[j] + sh2s[j], 0.f);
        acc += v * ow[j];
    }
    #pragma unroll
    for (int off = 32; off; off >>= 1)
        acc += __shfl_xor(acc, off, 64);
    if (lane == 0) {
        acc += feat[(size_t)b * 3 + 0] * ow[128]
             + feat[(size_t)b * 3 + 1] * ow[129]
             + feat[(size_t)b * 3 + 2] * ow[130]
             + ob[0];
        out[b] = acc;
    }
}

// ---------------------------------------------------------------------------
extern "C" void kernel_launch(void* const* d_in, const int* in_sizes, int n_in,
                              void* d_out, int out_size, void* d_ws, size_t ws_size,
                              hipStream_t stream)
{
    const int*   user_id = (const int*)d_in[0];
    const int*   item_id = (const int*)d_in[1];
    const int*   ufollow = (const int*)d_in[2];
    const int*   flen    = (const int*)d_in[3];
    const float* feat    = (const float*)d_in[4];
    const float* tag     = (const float*)d_in[5];
    const float* utab    = (const float*)d_in[6];
    const float* itab    = (const float*)d_in[7];
    const float* w1      = (const float*)d_in[8];
    const float* b1      = (const float*)d_in[9];
    const float* w2      = (const float*)d_in[10];
    const float* b2      = (const float*)d_in[11];
    const float* ow      = (const float*)d_in[12];
    const float* ob      = (const float*)d_in[13];
    const float* g1      = (const float*)d_in[14];
    const float* bb1     = (const float*)d_in[15];
    const float* g2      = (const float*)d_in[16];
    const float* bb2     = (const float*)d_in[17];

    float* ws     = (float*)d_ws;
    float* uemb   = ws;                          // 4096*128
    float* a1     = uemb + BATCH * DU;           // 4096*256
    float* a2     = a1 + BATCH * DI;             // 4096*128
    float* sum1   = a2 + BATCH * DU;             // 256  } contiguous 768-float
    float* sumsq1 = sum1 + 256;                  // 256  } region zeroed by
    float* sum2   = sumsq1 + 256;                // 128  } attn block 0
    float* sumsq2 = sum2 + 128;                  // 128  }

    attn_kernel<<<BATCH, 256, 0, stream>>>(user_id, ufollow, flen, utab, uemb,
                                           sum1);
    gemm1_kernel<<<dim3(64, 4), 512, 0, stream>>>(tag, item_id, itab, w1, b1, a1,
                                                  sum1, sumsq1);
    gemm2_kernel<<<dim3(128, 2), 256, 0, stream>>>(uemb, a1, sum1, sumsq1, g1, bb1,
                                                   w2, b2, a2, sum2, sumsq2);
    final_kernel<<<1024, 256, 0, stream>>>(a2, sum2, sumsq2, g2, bb2, feat, ow, ob,
                                           (float*)d_out);
}

// Round 4
// 283.023 us; speedup vs baseline: 1.1212x; 1.1212x over previous
//
#include <hip/hip_runtime.h>
#include <cstdint>
#include <cstddef>

#define BATCH 4096
#define F_FOLLOW 50
#define NROW 51            // 1 + F
#define DU 128
#define DI 256
#define DT 768
#define K1 (DT + DI)       // 1024
#define K2 (DU + DI)       // 384
#define EPS 1e-5f

typedef float f32x4 __attribute__((ext_vector_type(4)));
typedef short s16x8 __attribute__((ext_vector_type(8)));

#define MFMA16(a, b, c) __builtin_amdgcn_mfma_f32_16x16x32_bf16(a, b, c, 0, 0, 0)

// fp32 -> bf16 hi (truncate) + bf16 lo (RNE of residual): ~17-bit mantissa pair
__device__ __forceinline__ unsigned rne16(float r) {
    unsigned b = __float_as_uint(r);
    return (b + 0x7FFFu + ((b >> 16) & 1u)) >> 16;
}
__device__ __forceinline__ void cvt4(float4 v, unsigned &h0, unsigned &h1,
                                     unsigned &l0, unsigned &l1) {
    unsigned bx = __float_as_uint(v.x), by = __float_as_uint(v.y);
    unsigned bz = __float_as_uint(v.z), bw = __float_as_uint(v.w);
    h0 = (bx >> 16) | (by & 0xFFFF0000u);
    h1 = (bz >> 16) | (bw & 0xFFFF0000u);
    float rx = v.x - __uint_as_float(bx & 0xFFFF0000u);
    float ry = v.y - __uint_as_float(by & 0xFFFF0000u);
    float rz = v.z - __uint_as_float(bz & 0xFFFF0000u);
    float rw = v.w - __uint_as_float(bw & 0xFFFF0000u);
    l0 = rne16(rx) | (rne16(ry) << 16);
    l1 = rne16(rz) | (rne16(rw) << 16);
}

// ---------------------------------------------------------------------------
// Attention over [u, followed...] rows. One block (256 thr) per batch row.
// Rows beyond follow_len have softmax weight exactly 0 in the reference
// (masked to -1e9, exp underflows), so only valid rows are gathered.
// Block 0 zeroes the 768-float BN accumulator region.
// ---------------------------------------------------------------------------
__global__ __launch_bounds__(256) void attn_kernel(
    const int* __restrict__ user_id,
    const int* __restrict__ user_follow,
    const int* __restrict__ follow_len,
    const float* __restrict__ utab,     // [NU,128]
    float* __restrict__ uemb_out,       // [B,128]
    float* __restrict__ zero_region)    // [768] BN sum/sumsq accumulators
{
    __shared__ float uf[NROW * 133];
    __shared__ int   idx[NROW];
    __shared__ float w[NROW];
    __shared__ float sArr[64];
    __shared__ float pacc[256];

    const int b   = blockIdx.x;
    const int tid = threadIdx.x;

    if (b == 0)
        for (int i = tid; i < 768; i += 256) zero_region[i] = 0.f;

    const int fl = follow_len[b];
    const int nv = fl < F_FOLLOW ? fl : F_FOLLOW;    // last valid row index

    if (tid < NROW)
        idx[tid] = (tid == 0) ? user_id[b] : user_follow[b * F_FOLLOW + tid - 1];
    __syncthreads();

    const int nrows = nv + 1;
    for (int e = tid; e < nrows * 32; e += 256) {
        int n = e >> 5, d4 = (e & 31) << 2;
        float4 v = *(const float4*)(utab + (size_t)idx[n] * 128 + d4);
        float* dst = &uf[n * 133 + d4];
        dst[0] = v.x; dst[1] = v.y; dst[2] = v.z; dst[3] = v.w;
    }
    __syncthreads();

    // scores: all 256 threads; 4 lanes per row, 32 dims each (rotated start)
    {
        int n = tid >> 2, q = tid & 3;
        float acc = 0.f;
        if (n <= nv) {
            int d0 = q * 32;
            #pragma unroll 8
            for (int dd = 0; dd < 32; ++dd) {
                int d = d0 + ((dd + q * 8) & 31);
                acc += uf[n * 133 + d] * uf[d];
            }
        }
        acc += __shfl_xor(acc, 1);
        acc += __shfl_xor(acc, 2);
        if (q == 0 && n <= nv) sArr[n] = acc;
    }
    __syncthreads();

    if (tid < 64) {
        float s = (tid <= nv) ? sArr[tid] : -1e30f;
        float m = s;
        #pragma unroll
        for (int off = 32; off; off >>= 1)
            m = fmaxf(m, __shfl_xor(m, off, 64));
        float e = expf(s - m);
        float l = e;
        #pragma unroll
        for (int off = 32; off; off >>= 1)
            l += __shfl_xor(l, off, 64);
        if (tid <= nv) w[tid] = e / l;
    }
    __syncthreads();

    // weighted sum: two half-groups over rows, then combine
    {
        int d = tid & 127, half = tid >> 7;
        float o = 0.f;
        for (int n = half; n <= nv; n += 2)
            o += w[n] * uf[n * 133 + d];
        pacc[tid] = o;
    }
    __syncthreads();
    if (tid < 128) {
        float o = pacc[tid] + pacc[tid + 128];
        float outv = (fl > 1) ? o : uf[tid];
        uemb_out[(size_t)b * DU + tid] = outv;
    }
}

// ---------------------------------------------------------------------------
// GEMM1 (MFMA, split-bf16): a1 = [tag | item_emb] @ w1^T + b1 + item_emb.
// 64x64 tile, 256 thr = 4 waves in 2x2 layout, each wave 32x32 out via
// 2x2 16x16x32 tiles x 3 products (hh, hl, lh). Fused BN1 sum/sumsq.
// ---------------------------------------------------------------------------
__global__ __launch_bounds__(256) void gemm1_kernel(
    const float* __restrict__ tag,      // [B,768]
    const int*   __restrict__ item_id,
    const float* __restrict__ itab,     // [NI,256]
    const float* __restrict__ w1,       // [256,1024]
    const float* __restrict__ b1,       // [256]
    float* __restrict__ a1,             // [B,256]
    float* __restrict__ gsum,           // [256]
    float* __restrict__ gsq)            // [256]
{
    __shared__ __align__(16) unsigned short Ah[64][40], Al[64][40];
    __shared__ __align__(16) unsigned short Bh[64][40], Bl[64][40];
    __shared__ int   iid[64];
    __shared__ float lsum[64], lsq[64];

    const int tid = threadIdx.x;
    const int m0 = blockIdx.x * 64;
    const int n0 = blockIdx.y * 64;

    if (tid < 64) { iid[tid] = item_id[m0 + tid]; lsum[tid] = 0.f; lsq[tid] = 0.f; }

    const int r  = tid >> 2;           // staging row 0..63
    const int k8 = (tid & 3) * 8;      // staging k-offset 0,8,16,24

    const int w  = tid >> 6;           // wave 0..3
    const int l  = tid & 63;           // lane
    const int wr = (w >> 1) * 32;      // wave row base
    const int wc = (w & 1) * 32;       // wave col base
    const int fr = l & 15;             // frag row/col within 16-tile
    const int fk = (l >> 4) * 8;       // frag k offset

    f32x4 acc00 = {}, acc01 = {}, acc10 = {}, acc11 = {};

    // prologue: load K-step 0 (all-tag region)
    float4 ra0, ra1, rb0, rb1;
    {
        const float* ap = tag + (size_t)(m0 + r) * DT + k8;
        ra0 = *(const float4*)ap;  ra1 = *(const float4*)(ap + 4);
        const float* bp = w1 + (size_t)(n0 + r) * K1 + k8;
        rb0 = *(const float4*)bp;  rb1 = *(const float4*)(bp + 4);
    }
    __syncthreads();

    for (int kt = 0; kt < K1; kt += 32) {
        if (kt) __syncthreads();   // previous compute done reading LDS

        unsigned h0, h1, h2, h3, l0, l1, l2, l3;
        cvt4(ra0, h0, h1, l0, l1); cvt4(ra1, h2, h3, l2, l3);
        *(uint4*)&Ah[r][k8] = make_uint4(h0, h1, h2, h3);
        *(uint4*)&Al[r][k8] = make_uint4(l0, l1, l2, l3);
        cvt4(rb0, h0, h1, l0, l1); cvt4(rb1, h2, h3, l2, l3);
        *(uint4*)&Bh[r][k8] = make_uint4(h0, h1, h2, h3);
        *(uint4*)&Bl[r][k8] = make_uint4(l0, l1, l2, l3);

        if (kt + 32 < K1) {        // issue next tile's loads (latency hidden)
            const int kn = kt + 32;
            const float* ap;
            if (kn < DT) ap = tag + (size_t)(m0 + r) * DT + kn + k8;
            else         ap = itab + (size_t)iid[r] * DI + (kn - DT) + k8;
            ra0 = *(const float4*)ap;  ra1 = *(const float4*)(ap + 4);
            const float* bp = w1 + (size_t)(n0 + r) * K1 + kn + k8;
            rb0 = *(const float4*)bp;  rb1 = *(const float4*)(bp + 4);
        }
        __syncthreads();           // tile visible

        s16x8 ah0 = *(const s16x8*)&Ah[wr + fr][fk];
        s16x8 ah1 = *(const s16x8*)&Ah[wr + 16 + fr][fk];
        s16x8 al0 = *(const s16x8*)&Al[wr + fr][fk];
        s16x8 al1 = *(const s16x8*)&Al[wr + 16 + fr][fk];
        s16x8 bh0 = *(const s16x8*)&Bh[wc + fr][fk];
        s16x8 bh1 = *(const s16x8*)&Bh[wc + 16 + fr][fk];
        s16x8 bl0 = *(const s16x8*)&Bl[wc + fr][fk];
        s16x8 bl1 = *(const s16x8*)&Bl[wc + 16 + fr][fk];

        acc00 = MFMA16(ah0, bh0, acc00);
        acc01 = MFMA16(ah0, bh1, acc01);
        acc10 = MFMA16(ah1, bh0, acc10);
        acc11 = MFMA16(ah1, bh1, acc11);
        acc00 = MFMA16(ah0, bl0, acc00);
        acc01 = MFMA16(ah0, bl1, acc01);
        acc10 = MFMA16(ah1, bl0, acc10);
        acc11 = MFMA16(ah1, bl1, acc11);
        acc00 = MFMA16(al0, bh0, acc00);
        acc01 = MFMA16(al0, bh1, acc01);
        acc10 = MFMA16(al1, bh0, acc10);
        acc11 = MFMA16(al1, bh1, acc11);
    }

    // epilogue: C/D layout col=lane&15, row=(lane>>4)*4+reg
    const f32x4 accs[2][2] = {{acc00, acc01}, {acc10, acc11}};
    #pragma unroll
    for (int ct = 0; ct < 2; ++ct) {
        int cg  = wc + ct * 16 + fr;
        int col = n0 + cg;
        float bias = b1[col];
        float s_ = 0.f, q_ = 0.f;
        #pragma unroll
        for (int rt = 0; rt < 2; ++rt) {
            int rb = wr + rt * 16 + ((l >> 4) << 2);
            #pragma unroll
            for (int i = 0; i < 4; ++i) {
                int rl = rb + i;
                float v = accs[rt][ct][i] + bias + itab[(size_t)iid[rl] * DI + col];
                a1[(size_t)(m0 + rl) * DI + col] = v;
                s_ += v; q_ += v * v;
            }
        }
        s_ += __shfl_xor(s_, 16); s_ += __shfl_xor(s_, 32);
        q_ += __shfl_xor(q_, 16); q_ += __shfl_xor(q_, 32);
        if (l < 16) { atomicAdd(&lsum[cg], s_); atomicAdd(&lsq[cg], q_); }
    }
    __syncthreads();
    if (tid < 64) {
        atomicAdd(&gsum[n0 + tid], lsum[tid]);
        atomicAdd(&gsq [n0 + tid], lsq [tid]);
    }
}

// ---------------------------------------------------------------------------
// GEMM2 (MFMA, split-bf16): a2 = [uemb | relu(bn1(a1))] @ w2^T + b2 + uemb.
// bnprep1 folded into prologue; BN1 apply fused into A staging; BN2 stats fused.
// ---------------------------------------------------------------------------
__global__ __launch_bounds__(256) void gemm2_kernel(
    const float* __restrict__ uemb,    // [B,128]
    const float* __restrict__ a1,      // [B,256]
    const float* __restrict__ gsum1,   // [256]
    const float* __restrict__ gsq1,    // [256]
    const float* __restrict__ g1,      // [256]
    const float* __restrict__ bb1,     // [256]
    const float* __restrict__ w2,      // [128,384]
    const float* __restrict__ b2,      // [128]
    float* __restrict__ a2,            // [B,128]
    float* __restrict__ gsum,          // [128]
    float* __restrict__ gsq)           // [128]
{
    __shared__ __align__(16) unsigned short Ah[64][40], Al[64][40];
    __shared__ __align__(16) unsigned short Bh[64][40], Bl[64][40];
    __shared__ __align__(16) float sc1s[256], sh1s[256];
    __shared__ float lsum[64], lsq[64];

    const int tid = threadIdx.x;
    const int m0 = blockIdx.x * 64;
    const int n0 = blockIdx.y * 64;

    {   // folded bnprep1: one column per thread
        float mean = gsum1[tid] * (1.f / 4096.f);
        float var  = gsq1[tid] * (1.f / 4096.f) - mean * mean;
        var = fmaxf(var, 0.f);
        float sc = g1[tid] / sqrtf(var + EPS);
        sc1s[tid] = sc;
        sh1s[tid] = bb1[tid] - mean * sc;
    }
    if (tid < 64) { lsum[tid] = 0.f; lsq[tid] = 0.f; }

    const int r  = tid >> 2;
    const int k8 = (tid & 3) * 8;
    const int w  = tid >> 6;
    const int l  = tid & 63;
    const int wr = (w >> 1) * 32;
    const int wc = (w & 1) * 32;
    const int fr = l & 15;
    const int fk = (l >> 4) * 8;

    f32x4 acc00 = {}, acc01 = {}, acc10 = {}, acc11 = {};

    float4 ra0, ra1, rb0, rb1;
    {   // K-step 0 is all-uemb region
        const float* ap = uemb + (size_t)(m0 + r) * DU + k8;
        ra0 = *(const float4*)ap;  ra1 = *(const float4*)(ap + 4);
        const float* bp = w2 + (size_t)(n0 + r) * K2 + k8;
        rb0 = *(const float4*)bp;  rb1 = *(const float4*)(bp + 4);
    }
    __syncthreads();

    for (int kt = 0; kt < K2; kt += 32) {
        if (kt) __syncthreads();

        unsigned h0, h1, h2, h3, l0, l1, l2, l3;
        cvt4(ra0, h0, h1, l0, l1); cvt4(ra1, h2, h3, l2, l3);
        *(uint4*)&Ah[r][k8] = make_uint4(h0, h1, h2, h3);
        *(uint4*)&Al[r][k8] = make_uint4(l0, l1, l2, l3);
        cvt4(rb0, h0, h1, l0, l1); cvt4(rb1, h2, h3, l2, l3);
        *(uint4*)&Bh[r][k8] = make_uint4(h0, h1, h2, h3);
        *(uint4*)&Bl[r][k8] = make_uint4(l0, l1, l2, l3);

        if (kt + 32 < K2) {
            const int kn = kt + 32;
            if (kn < DU) {
                const float* ap = uemb + (size_t)(m0 + r) * DU + kn + k8;
                ra0 = *(const float4*)ap;  ra1 = *(const float4*)(ap + 4);
            } else {
                int c = kn + k8 - DU;
                float4 v0 = *(const float4*)(a1 + (size_t)(m0 + r) * DI + c);
                float4 v1 = *(const float4*)(a1 + (size_t)(m0 + r) * DI + c + 4);
                float4 s0 = *(const float4*)&sc1s[c];
                float4 s1 = *(const float4*)&sc1s[c + 4];
                float4 h0v = *(const float4*)&sh1s[c];
                float4 h1v = *(const float4*)&sh1s[c + 4];
                ra0.x = fmaxf(v0.x * s0.x + h0v.x, 0.f);
                ra0.y = fmaxf(v0.y * s0.y + h0v.y, 0.f);
                ra0.z = fmaxf(v0.z * s0.z + h0v.z, 0.f);
                ra0.w = fmaxf(v0.w * s0.w + h0v.w, 0.f);
                ra1.x = fmaxf(v1.x * s1.x + h1v.x, 0.f);
                ra1.y = fmaxf(v1.y * s1.y + h1v.y, 0.f);
                ra1.z = fmaxf(v1.z * s1.z + h1v.z, 0.f);
                ra1.w = fmaxf(v1.w * s1.w + h1v.w, 0.f);
            }
            const float* bp = w2 + (size_t)(n0 + r) * K2 + kn + k8;
            rb0 = *(const float4*)bp;  rb1 = *(const float4*)(bp + 4);
        }
        __syncthreads();

        s16x8 ah0 = *(const s16x8*)&Ah[wr + fr][fk];
        s16x8 ah1 = *(const s16x8*)&Ah[wr + 16 + fr][fk];
        s16x8 al0 = *(const s16x8*)&Al[wr + fr][fk];
        s16x8 al1 = *(const s16x8*)&Al[wr + 16 + fr][fk];
        s16x8 bh0 = *(const s16x8*)&Bh[wc + fr][fk];
        s16x8 bh1 = *(const s16x8*)&Bh[wc + 16 + fr][fk];
        s16x8 bl0 = *(const s16x8*)&Bl[wc + fr][fk];
        s16x8 bl1 = *(const s16x8*)&Bl[wc + 16 + fr][fk];

        acc00 = MFMA16(ah0, bh0, acc00);
        acc01 = MFMA16(ah0, bh1, acc01);
        acc10 = MFMA16(ah1, bh0, acc10);
        acc11 = MFMA16(ah1, bh1, acc11);
        acc00 = MFMA16(ah0, bl0, acc00);
        acc01 = MFMA16(ah0, bl1, acc01);
        acc10 = MFMA16(ah1, bl0, acc10);
        acc11 = MFMA16(ah1, bl1, acc11);
        acc00 = MFMA16(al0, bh0, acc00);
        acc01 = MFMA16(al0, bh1, acc01);
        acc10 = MFMA16(al1, bh0, acc10);
        acc11 = MFMA16(al1, bh1, acc11);
    }

    const f32x4 accs[2][2] = {{acc00, acc01}, {acc10, acc11}};
    #pragma unroll
    for (int ct = 0; ct < 2; ++ct) {
        int cg  = wc + ct * 16 + fr;
        int col = n0 + cg;
        float bias = b2[col];
        float s_ = 0.f, q_ = 0.f;
        #pragma unroll
        for (int rt = 0; rt < 2; ++rt) {
            int rb = wr + rt * 16 + ((l >> 4) << 2);
            #pragma unroll
            for (int i = 0; i < 4; ++i) {
                int rl = rb + i;
                float v = accs[rt][ct][i] + bias + uemb[(size_t)(m0 + rl) * DU + col];
                a2[(size_t)(m0 + rl) * DU + col] = v;
                s_ += v; q_ += v * v;
            }
        }
        s_ += __shfl_xor(s_, 16); s_ += __shfl_xor(s_, 32);
        q_ += __shfl_xor(q_, 16); q_ += __shfl_xor(q_, 32);
        if (l < 16) { atomicAdd(&lsum[cg], s_); atomicAdd(&lsq[cg], q_); }
    }
    __syncthreads();
    if (tid < 64) {
        atomicAdd(&gsum[n0 + tid], lsum[tid]);
        atomicAdd(&gsq [n0 + tid], lsq [tid]);
    }
}

// ---------------------------------------------------------------------------
// Final: logits = [relu(bn2(a2)) | feat] @ out_w^T + out_b. One wave per row.
// ---------------------------------------------------------------------------
__global__ __launch_bounds__(256) void final_kernel(
    const float* __restrict__ a2,
    const float* __restrict__ gsum2,   // [128]
    const float* __restrict__ gsq2,    // [128]
    const float* __restrict__ g2,      // [128]
    const float* __restrict__ bb2,     // [128]
    const float* __restrict__ feat,
    const float* __restrict__ ow, const float* __restrict__ ob,
    float* __restrict__ out)
{
    __shared__ float sc2s[128];
    __shared__ float sh2s[128];

    const int tid  = threadIdx.x;
    if (tid < 128) {
        float mean = gsum2[tid] * (1.f / 4096.f);
        float var  = gsq2[tid] * (1.f / 4096.f) - mean * mean;
        var = fmaxf(var, 0.f);
        float sc = g2[tid] / sqrtf(var + EPS);
        sc2s[tid] = sc;
        sh2s[tid] = bb2[tid] - mean * sc;
    }
    __syncthreads();

    const int lane = tid & 63;
    const int wv   = tid >> 6;
    const int b    = blockIdx.x * 4 + wv;

    float acc = 0.f;
    #pragma unroll
    for (int h = 0; h < 2; ++h) {
        int j = lane + h * 64;
        float v = fmaxf(a2[(size_t)b * DU + j] * sc2s[j] + sh2s[j], 0.f);
        acc += v * ow[j];
    }
    #pragma unroll
    for (int off = 32; off; off >>= 1)
        acc += __shfl_xor(acc, off, 64);
    if (lane == 0) {
        acc += feat[(size_t)b * 3 + 0] * ow[128]
             + feat[(size_t)b * 3 + 1] * ow[129]
             + feat[(size_t)b * 3 + 2] * ow[130]
             + ob[0];
        out[b] = acc;
    }
}

// ---------------------------------------------------------------------------
extern "C" void kernel_launch(void* const* d_in, const int* in_sizes, int n_in,
                              void* d_out, int out_size, void* d_ws, size_t ws_size,
                              hipStream_t stream)
{
    const int*   user_id = (const int*)d_in[0];
    const int*   item_id = (const int*)d_in[1];
    const int*   ufollow = (const int*)d_in[2];
    const int*   flen    = (const int*)d_in[3];
    const float* feat    = (const float*)d_in[4];
    const float* tag     = (const float*)d_in[5];
    const float* utab    = (const float*)d_in[6];
    const float* itab    = (const float*)d_in[7];
    const float* w1      = (const float*)d_in[8];
    const float* b1      = (const float*)d_in[9];
    const float* w2      = (const float*)d_in[10];
    const float* b2      = (const float*)d_in[11];
    const float* ow      = (const float*)d_in[12];
    const float* ob      = (const float*)d_in[13];
    const float* g1      = (const float*)d_in[14];
    const float* bb1     = (const float*)d_in[15];
    const float* g2      = (const float*)d_in[16];
    const float* bb2     = (const float*)d_in[17];

    float* ws     = (float*)d_ws;
    float* uemb   = ws;                          // 4096*128
    float* a1     = uemb + BATCH * DU;           // 4096*256
    float* a2     = a1 + BATCH * DI;             // 4096*128
    float* sum1   = a2 + BATCH * DU;             // 256  } contiguous 768-float
    float* sumsq1 = sum1 + 256;                  // 256  } region zeroed by
    float* sum2   = sumsq1 + 256;                // 128  } attn block 0
    float* sumsq2 = sum2 + 128;                  // 128  }

    attn_kernel<<<BATCH, 256, 0, stream>>>(user_id, ufollow, flen, utab, uemb,
                                           sum1);
    gemm1_kernel<<<dim3(64, 4), 256, 0, stream>>>(tag, item_id, itab, w1, b1, a1,
                                                  sum1, sumsq1);
    gemm2_kernel<<<dim3(64, 2), 256, 0, stream>>>(uemb, a1, sum1, sumsq1, g1, bb1,
                                                  w2, b2, a2, sum2, sumsq2);
    final_kernel<<<1024, 256, 0, stream>>>(a2, sum2, sumsq2, g2, bb2, feat, ow, ob,
                                           (float*)d_out);
}

// Round 5
// 267.733 us; speedup vs baseline: 1.1852x; 1.0571x over previous
//
#include <hip/hip_runtime.h>
#include <cstdint>
#include <cstddef>

#define BATCH 4096
#define F_FOLLOW 50
#define NROW 51            // 1 + F
#define DU 128
#define DI 256
#define DT 768
#define K1 (DT + DI)       // 1024
#define K2 (DU + DI)       // 384
#define EPS 1e-5f

typedef float f32x4 __attribute__((ext_vector_type(4)));
typedef short s16x8 __attribute__((ext_vector_type(8)));

#define MFMA16(a, b, c) __builtin_amdgcn_mfma_f32_16x16x32_bf16(a, b, c, 0, 0, 0)

// fp32 -> bf16 hi (truncate) + bf16 lo (RNE of residual): ~17-bit mantissa pair
__device__ __forceinline__ unsigned rne16(float r) {
    unsigned b = __float_as_uint(r);
    return (b + 0x7FFFu + ((b >> 16) & 1u)) >> 16;
}
__device__ __forceinline__ void cvt4(float4 v, unsigned &h0, unsigned &h1,
                                     unsigned &l0, unsigned &l1) {
    unsigned bx = __float_as_uint(v.x), by = __float_as_uint(v.y);
    unsigned bz = __float_as_uint(v.z), bw = __float_as_uint(v.w);
    h0 = (bx >> 16) | (by & 0xFFFF0000u);
    h1 = (bz >> 16) | (bw & 0xFFFF0000u);
    float rx = v.x - __uint_as_float(bx & 0xFFFF0000u);
    float ry = v.y - __uint_as_float(by & 0xFFFF0000u);
    float rz = v.z - __uint_as_float(bz & 0xFFFF0000u);
    float rw = v.w - __uint_as_float(bw & 0xFFFF0000u);
    l0 = rne16(rx) | (rne16(ry) << 16);
    l1 = rne16(rz) | (rne16(rw) << 16);
}

struct AttnSmem {
    float uf[NROW * 133];
    int   idx[NROW];
    float w[NROW];
    float sArr[64];
    float pacc[256];
};
struct Gemm1Smem {
    unsigned short Ah[64][40], Al[64][40], Bh[64][40], Bl[64][40];
    int   iid[64];
    float lsum[64], lsq[64];
};
union __align__(16) FusedSmem { AttnSmem a; Gemm1Smem g; };

// ---------------------------------------------------------------------------
// Mega-kernel: blocks 0..255 run GEMM1 (MFMA split-bf16, 64x64 tile), blocks
// 256..4351 run attention (one block per batch row). The two are independent
// (attn->uemb first consumed by gemm2), so they overlap: attn is gather/
// latency-bound, gemm1 is LDS/MFMA-bound.
// ---------------------------------------------------------------------------
__global__ __launch_bounds__(256) void fused_attn_gemm1(
    const int* __restrict__ user_id,
    const int* __restrict__ user_follow,
    const int* __restrict__ follow_len,
    const float* __restrict__ utab,     // [NU,128]
    const float* __restrict__ tag,      // [B,768]
    const int*   __restrict__ item_id,
    const float* __restrict__ itab,     // [NI,256]
    const float* __restrict__ w1,       // [256,1024]
    const float* __restrict__ b1,       // [256]
    float* __restrict__ uemb_out,       // [B,128]
    float* __restrict__ a1,             // [B,256]
    float* __restrict__ part1s,         // [256][64] per-(col, m-block) sums
    float* __restrict__ part1q)         // [256][64]
{
    __shared__ FusedSmem sm;
    const int tid = threadIdx.x;

    if (blockIdx.x < 256) {
        // =================== GEMM1 path ===================
        auto& G = sm.g;
        const int bm = blockIdx.x >> 2;
        const int m0 = bm * 64;
        const int n0 = (blockIdx.x & 3) * 64;

        if (tid < 64) { G.iid[tid] = item_id[m0 + tid]; G.lsum[tid] = 0.f; G.lsq[tid] = 0.f; }

        const int r  = tid >> 2;           // staging row 0..63
        const int k8 = (tid & 3) * 8;      // staging k-offset 0,8,16,24
        const int w  = tid >> 6;           // wave 0..3
        const int l  = tid & 63;
        const int wr = (w >> 1) * 32;
        const int wc = (w & 1) * 32;
        const int fr = l & 15;
        const int fk = (l >> 4) * 8;

        f32x4 acc00 = {}, acc01 = {}, acc10 = {}, acc11 = {};

        float4 ra0, ra1, rb0, rb1;
        {   // prologue: K-step 0 (all-tag region)
            const float* ap = tag + (size_t)(m0 + r) * DT + k8;
            ra0 = *(const float4*)ap;  ra1 = *(const float4*)(ap + 4);
            const float* bp = w1 + (size_t)(n0 + r) * K1 + k8;
            rb0 = *(const float4*)bp;  rb1 = *(const float4*)(bp + 4);
        }
        __syncthreads();

        for (int kt = 0; kt < K1; kt += 32) {
            if (kt) __syncthreads();

            unsigned h0, h1, h2, h3, l0, l1, l2, l3;
            cvt4(ra0, h0, h1, l0, l1); cvt4(ra1, h2, h3, l2, l3);
            *(uint4*)&G.Ah[r][k8] = make_uint4(h0, h1, h2, h3);
            *(uint4*)&G.Al[r][k8] = make_uint4(l0, l1, l2, l3);
            cvt4(rb0, h0, h1, l0, l1); cvt4(rb1, h2, h3, l2, l3);
            *(uint4*)&G.Bh[r][k8] = make_uint4(h0, h1, h2, h3);
            *(uint4*)&G.Bl[r][k8] = make_uint4(l0, l1, l2, l3);

            if (kt + 32 < K1) {
                const int kn = kt + 32;
                const float* ap;
                if (kn < DT) ap = tag + (size_t)(m0 + r) * DT + kn + k8;
                else         ap = itab + (size_t)G.iid[r] * DI + (kn - DT) + k8;
                ra0 = *(const float4*)ap;  ra1 = *(const float4*)(ap + 4);
                const float* bp = w1 + (size_t)(n0 + r) * K1 + kn + k8;
                rb0 = *(const float4*)bp;  rb1 = *(const float4*)(bp + 4);
            }
            __syncthreads();

            s16x8 ah0 = *(const s16x8*)&G.Ah[wr + fr][fk];
            s16x8 ah1 = *(const s16x8*)&G.Ah[wr + 16 + fr][fk];
            s16x8 al0 = *(const s16x8*)&G.Al[wr + fr][fk];
            s16x8 al1 = *(const s16x8*)&G.Al[wr + 16 + fr][fk];
            s16x8 bh0 = *(const s16x8*)&G.Bh[wc + fr][fk];
            s16x8 bh1 = *(const s16x8*)&G.Bh[wc + 16 + fr][fk];
            s16x8 bl0 = *(const s16x8*)&G.Bl[wc + fr][fk];
            s16x8 bl1 = *(const s16x8*)&G.Bl[wc + 16 + fr][fk];

            acc00 = MFMA16(ah0, bh0, acc00);
            acc01 = MFMA16(ah0, bh1, acc01);
            acc10 = MFMA16(ah1, bh0, acc10);
            acc11 = MFMA16(ah1, bh1, acc11);
            acc00 = MFMA16(ah0, bl0, acc00);
            acc01 = MFMA16(ah0, bl1, acc01);
            acc10 = MFMA16(ah1, bl0, acc10);
            acc11 = MFMA16(ah1, bl1, acc11);
            acc00 = MFMA16(al0, bh0, acc00);
            acc01 = MFMA16(al0, bh1, acc01);
            acc10 = MFMA16(al1, bh0, acc10);
            acc11 = MFMA16(al1, bh1, acc11);
        }

        // epilogue: C/D layout col=lane&15, row=(lane>>4)*4+reg
        const f32x4 accs[2][2] = {{acc00, acc01}, {acc10, acc11}};
        #pragma unroll
        for (int ct = 0; ct < 2; ++ct) {
            int cg  = wc + ct * 16 + fr;
            int col = n0 + cg;
            float bias = b1[col];
            float s_ = 0.f, q_ = 0.f;
            #pragma unroll
            for (int rt = 0; rt < 2; ++rt) {
                int rb = wr + rt * 16 + ((l >> 4) << 2);
                #pragma unroll
                for (int i = 0; i < 4; ++i) {
                    int rl = rb + i;
                    float v = accs[rt][ct][i] + bias + itab[(size_t)G.iid[rl] * DI + col];
                    a1[(size_t)(m0 + rl) * DI + col] = v;
                    s_ += v; q_ += v * v;
                }
            }
            s_ += __shfl_xor(s_, 16); s_ += __shfl_xor(s_, 32);
            q_ += __shfl_xor(q_, 16); q_ += __shfl_xor(q_, 32);
            if (l < 16) { atomicAdd(&G.lsum[cg], s_); atomicAdd(&G.lsq[cg], q_); }
        }
        __syncthreads();
        if (tid < 64) {
            part1s[(size_t)(n0 + tid) * 64 + bm] = G.lsum[tid];
            part1q[(size_t)(n0 + tid) * 64 + bm] = G.lsq[tid];
        }
    } else {
        // =================== attention path ===================
        auto& A = sm.a;
        const int b  = blockIdx.x - 256;
        const int fl = follow_len[b];
        const int nv = fl < F_FOLLOW ? fl : F_FOLLOW;    // last valid row index

        if (tid < NROW)
            A.idx[tid] = (tid == 0) ? user_id[b] : user_follow[b * F_FOLLOW + tid - 1];
        __syncthreads();

        const int nrows = nv + 1;
        for (int e = tid; e < nrows * 32; e += 256) {
            int n = e >> 5, d4 = (e & 31) << 2;
            float4 v = *(const float4*)(utab + (size_t)A.idx[n] * 128 + d4);
            float* dst = &A.uf[n * 133 + d4];
            dst[0] = v.x; dst[1] = v.y; dst[2] = v.z; dst[3] = v.w;
        }
        __syncthreads();

        // scores: 4 lanes per row, 32 dims each (rotated start)
        {
            int n = tid >> 2, q = tid & 3;
            float acc = 0.f;
            if (n <= nv) {
                int d0 = q * 32;
                #pragma unroll 8
                for (int dd = 0; dd < 32; ++dd) {
                    int d = d0 + ((dd + q * 8) & 31);
                    acc += A.uf[n * 133 + d] * A.uf[d];   // uf[d] == u[d]
                }
            }
            acc += __shfl_xor(acc, 1);
            acc += __shfl_xor(acc, 2);
            if (q == 0 && n <= nv) A.sArr[n] = acc;
        }
        __syncthreads();

        if (tid < 64) {
            float s = (tid <= nv) ? A.sArr[tid] : -1e30f;
            float m = s;
            #pragma unroll
            for (int off = 32; off; off >>= 1)
                m = fmaxf(m, __shfl_xor(m, off, 64));
            float e = expf(s - m);
            float l2 = e;
            #pragma unroll
            for (int off = 32; off; off >>= 1)
                l2 += __shfl_xor(l2, off, 64);
            if (tid <= nv) A.w[tid] = e / l2;
        }
        __syncthreads();

        // weighted sum: two half-groups over rows, then combine
        {
            int d = tid & 127, half = tid >> 7;
            float o = 0.f;
            for (int n = half; n <= nv; n += 2)
                o += A.w[n] * A.uf[n * 133 + d];
            A.pacc[tid] = o;
        }
        __syncthreads();
        if (tid < 128) {
            float o = A.pacc[tid] + A.pacc[tid + 128];
            float outv = (fl > 1) ? o : A.uf[tid];
            uemb_out[(size_t)b * DU + tid] = outv;
        }
    }
}

// ---------------------------------------------------------------------------
// GEMM2 (MFMA, split-bf16): a2 = [uemb | relu(bn1(a1))] @ w2^T + b2 + uemb.
// BN1 scale/shift reduced from per-block partials in the prologue; BN2
// per-block partials written in the epilogue (no global atomics anywhere).
// ---------------------------------------------------------------------------
__global__ __launch_bounds__(256) void gemm2_kernel(
    const float* __restrict__ uemb,    // [B,128]
    const float* __restrict__ a1,      // [B,256]
    const float* __restrict__ part1s,  // [256][64]
    const float* __restrict__ part1q,  // [256][64]
    const float* __restrict__ g1,      // [256]
    const float* __restrict__ bb1,     // [256]
    const float* __restrict__ w2,      // [128,384]
    const float* __restrict__ b2,      // [128]
    float* __restrict__ a2,            // [B,128]
    float* __restrict__ part2s,        // [128][64]
    float* __restrict__ part2q)        // [128][64]
{
    __shared__ __align__(16) unsigned short Ah[64][40], Al[64][40];
    __shared__ __align__(16) unsigned short Bh[64][40], Bl[64][40];
    __shared__ __align__(16) float sc1s[256], sh1s[256];
    __shared__ float lsum[64], lsq[64];

    const int tid = threadIdx.x;
    const int bm = blockIdx.x;
    const int m0 = bm * 64;
    const int n0 = blockIdx.y * 64;

    {   // folded bnprep1 from partials: one column per thread
        const float4* ps = (const float4*)(part1s + (size_t)tid * 64);
        const float4* pq = (const float4*)(part1q + (size_t)tid * 64);
        float s = 0.f, q = 0.f;
        #pragma unroll
        for (int j = 0; j < 16; ++j) {
            float4 v = ps[j]; s += v.x + v.y + v.z + v.w;
            float4 u = pq[j]; q += u.x + u.y + u.z + u.w;
        }
        float mean = s * (1.f / 4096.f);
        float var  = fmaxf(q * (1.f / 4096.f) - mean * mean, 0.f);
        float sc = g1[tid] / sqrtf(var + EPS);
        sc1s[tid] = sc;
        sh1s[tid] = bb1[tid] - mean * sc;
    }
    if (tid < 64) { lsum[tid] = 0.f; lsq[tid] = 0.f; }

    const int r  = tid >> 2;
    const int k8 = (tid & 3) * 8;
    const int w  = tid >> 6;
    const int l  = tid & 63;
    const int wr = (w >> 1) * 32;
    const int wc = (w & 1) * 32;
    const int fr = l & 15;
    const int fk = (l >> 4) * 8;

    f32x4 acc00 = {}, acc01 = {}, acc10 = {}, acc11 = {};

    float4 ra0, ra1, rb0, rb1;
    {   // K-step 0 is all-uemb region
        const float* ap = uemb + (size_t)(m0 + r) * DU + k8;
        ra0 = *(const float4*)ap;  ra1 = *(const float4*)(ap + 4);
        const float* bp = w2 + (size_t)(n0 + r) * K2 + k8;
        rb0 = *(const float4*)bp;  rb1 = *(const float4*)(bp + 4);
    }
    __syncthreads();

    for (int kt = 0; kt < K2; kt += 32) {
        if (kt) __syncthreads();

        unsigned h0, h1, h2, h3, l0, l1, l2, l3;
        cvt4(ra0, h0, h1, l0, l1); cvt4(ra1, h2, h3, l2, l3);
        *(uint4*)&Ah[r][k8] = make_uint4(h0, h1, h2, h3);
        *(uint4*)&Al[r][k8] = make_uint4(l0, l1, l2, l3);
        cvt4(rb0, h0, h1, l0, l1); cvt4(rb1, h2, h3, l2, l3);
        *(uint4*)&Bh[r][k8] = make_uint4(h0, h1, h2, h3);
        *(uint4*)&Bl[r][k8] = make_uint4(l0, l1, l2, l3);

        if (kt + 32 < K2) {
            const int kn = kt + 32;
            if (kn < DU) {
                const float* ap = uemb + (size_t)(m0 + r) * DU + kn + k8;
                ra0 = *(const float4*)ap;  ra1 = *(const float4*)(ap + 4);
            } else {
                int c = kn + k8 - DU;
                float4 v0 = *(const float4*)(a1 + (size_t)(m0 + r) * DI + c);
                float4 v1 = *(const float4*)(a1 + (size_t)(m0 + r) * DI + c + 4);
                float4 s0 = *(const float4*)&sc1s[c];
                float4 s1 = *(const float4*)&sc1s[c + 4];
                float4 h0v = *(const float4*)&sh1s[c];
                float4 h1v = *(const float4*)&sh1s[c + 4];
                ra0.x = fmaxf(v0.x * s0.x + h0v.x, 0.f);
                ra0.y = fmaxf(v0.y * s0.y + h0v.y, 0.f);
                ra0.z = fmaxf(v0.z * s0.z + h0v.z, 0.f);
                ra0.w = fmaxf(v0.w * s0.w + h0v.w, 0.f);
                ra1.x = fmaxf(v1.x * s1.x + h1v.x, 0.f);
                ra1.y = fmaxf(v1.y * s1.y + h1v.y, 0.f);
                ra1.z = fmaxf(v1.z * s1.z + h1v.z, 0.f);
                ra1.w = fmaxf(v1.w * s1.w + h1v.w, 0.f);
            }
            const float* bp = w2 + (size_t)(n0 + r) * K2 + kn + k8;
            rb0 = *(const float4*)bp;  rb1 = *(const float4*)(bp + 4);
        }
        __syncthreads();

        s16x8 ah0 = *(const s16x8*)&Ah[wr + fr][fk];
        s16x8 ah1 = *(const s16x8*)&Ah[wr + 16 + fr][fk];
        s16x8 al0 = *(const s16x8*)&Al[wr + fr][fk];
        s16x8 al1 = *(const s16x8*)&Al[wr + 16 + fr][fk];
        s16x8 bh0 = *(const s16x8*)&Bh[wc + fr][fk];
        s16x8 bh1 = *(const s16x8*)&Bh[wc + 16 + fr][fk];
        s16x8 bl0 = *(const s16x8*)&Bl[wc + fr][fk];
        s16x8 bl1 = *(const s16x8*)&Bl[wc + 16 + fr][fk];

        acc00 = MFMA16(ah0, bh0, acc00);
        acc01 = MFMA16(ah0, bh1, acc01);
        acc10 = MFMA16(ah1, bh0, acc10);
        acc11 = MFMA16(ah1, bh1, acc11);
        acc00 = MFMA16(ah0, bl0, acc00);
        acc01 = MFMA16(ah0, bl1, acc01);
        acc10 = MFMA16(ah1, bl0, acc10);
        acc11 = MFMA16(ah1, bl1, acc11);
        acc00 = MFMA16(al0, bh0, acc00);
        acc01 = MFMA16(al0, bh1, acc01);
        acc10 = MFMA16(al1, bh0, acc10);
        acc11 = MFMA16(al1, bh1, acc11);
    }

    const f32x4 accs[2][2] = {{acc00, acc01}, {acc10, acc11}};
    #pragma unroll
    for (int ct = 0; ct < 2; ++ct) {
        int cg  = wc + ct * 16 + fr;
        int col = n0 + cg;
        float bias = b2[col];
        float s_ = 0.f, q_ = 0.f;
        #pragma unroll
        for (int rt = 0; rt < 2; ++rt) {
            int rb = wr + rt * 16 + ((l >> 4) << 2);
            #pragma unroll
            for (int i = 0; i < 4; ++i) {
                int rl = rb + i;
                float v = accs[rt][ct][i] + bias + uemb[(size_t)(m0 + rl) * DU + col];
                a2[(size_t)(m0 + rl) * DU + col] = v;
                s_ += v; q_ += v * v;
            }
        }
        s_ += __shfl_xor(s_, 16); s_ += __shfl_xor(s_, 32);
        q_ += __shfl_xor(q_, 16); q_ += __shfl_xor(q_, 32);
        if (l < 16) { atomicAdd(&lsum[cg], s_); atomicAdd(&lsq[cg], q_); }
    }
    __syncthreads();
    if (tid < 64) {
        part2s[(size_t)(n0 + tid) * 64 + bm] = lsum[tid];
        part2q[(size_t)(n0 + tid) * 64 + bm] = lsq[tid];
    }
}

// ---------------------------------------------------------------------------
// Final: logits = [relu(bn2(a2)) | feat] @ out_w^T + out_b.
// 256 blocks x 16 rows; BN2 scale/shift reduced from partials per block.
// ---------------------------------------------------------------------------
__global__ __launch_bounds__(256) void final_kernel(
    const float* __restrict__ a2,
    const float* __restrict__ part2s,  // [128][64]
    const float* __restrict__ part2q,  // [128][64]
    const float* __restrict__ g2,      // [128]
    const float* __restrict__ bb2,     // [128]
    const float* __restrict__ feat,
    const float* __restrict__ ow, const float* __restrict__ ob,
    float* __restrict__ out)
{
    __shared__ float sc2s[128];
    __shared__ float sh2s[128];

    const int tid = threadIdx.x;
    if (tid < 128) {
        const float4* ps = (const float4*)(part2s + (size_t)tid * 64);
        const float4* pq = (const float4*)(part2q + (size_t)tid * 64);
        float s = 0.f, q = 0.f;
        #pragma unroll
        for (int j = 0; j < 16; ++j) {
            float4 v = ps[j]; s += v.x + v.y + v.z + v.w;
            float4 u = pq[j]; q += u.x + u.y + u.z + u.w;
        }
        float mean = s * (1.f / 4096.f);
        float var  = fmaxf(q * (1.f / 4096.f) - mean * mean, 0.f);
        float sc = g2[tid] / sqrtf(var + EPS);
        sc2s[tid] = sc;
        sh2s[tid] = bb2[tid] - mean * sc;
    }
    __syncthreads();

    const int lane = tid & 63;
    const int wv   = tid >> 6;

    #pragma unroll
    for (int rr = 0; rr < 4; ++rr) {
        const int b = blockIdx.x * 16 + wv * 4 + rr;
        float acc = 0.f;
        #pragma unroll
        for (int h = 0; h < 2; ++h) {
            int j = lane + h * 64;
            float v = fmaxf(a2[(size_t)b * DU + j] * sc2s[j] + sh2s[j], 0.f);
            acc += v * ow[j];
        }
        #pragma unroll
        for (int off = 32; off; off >>= 1)
            acc += __shfl_xor(acc, off, 64);
        if (lane == 0) {
            acc += feat[(size_t)b * 3 + 0] * ow[128]
                 + feat[(size_t)b * 3 + 1] * ow[129]
                 + feat[(size_t)b * 3 + 2] * ow[130]
                 + ob[0];
            out[b] = acc;
        }
    }
}

// ---------------------------------------------------------------------------
extern "C" void kernel_launch(void* const* d_in, const int* in_sizes, int n_in,
                              void* d_out, int out_size, void* d_ws, size_t ws_size,
                              hipStream_t stream)
{
    const int*   user_id = (const int*)d_in[0];
    const int*   item_id = (const int*)d_in[1];
    const int*   ufollow = (const int*)d_in[2];
    const int*   flen    = (const int*)d_in[3];
    const float* feat    = (const float*)d_in[4];
    const float* tag     = (const float*)d_in[5];
    const float* utab    = (const float*)d_in[6];
    const float* itab    = (const float*)d_in[7];
    const float* w1      = (const float*)d_in[8];
    const float* b1      = (const float*)d_in[9];
    const float* w2      = (const float*)d_in[10];
    const float* b2      = (const float*)d_in[11];
    const float* ow      = (const float*)d_in[12];
    const float* ob      = (const float*)d_in[13];
    const float* g1      = (const float*)d_in[14];
    const float* bb1     = (const float*)d_in[15];
    const float* g2      = (const float*)d_in[16];
    const float* bb2     = (const float*)d_in[17];

    float* ws     = (float*)d_ws;
    float* uemb   = ws;                          // 4096*128
    float* a1     = uemb + BATCH * DU;           // 4096*256
    float* a2     = a1 + BATCH * DI;             // 4096*128
    float* part1s = a2 + BATCH * DU;             // 256*64
    float* part1q = part1s + 256 * 64;           // 256*64
    float* part2s = part1q + 256 * 64;           // 128*64
    float* part2q = part2s + 128 * 64;           // 128*64

    fused_attn_gemm1<<<4352, 256, 0, stream>>>(user_id, ufollow, flen, utab,
                                               tag, item_id, itab, w1, b1,
                                               uemb, a1, part1s, part1q);
    gemm2_kernel<<<dim3(64, 2), 256, 0, stream>>>(uemb, a1, part1s, part1q, g1, bb1,
                                                  w2, b2, a2, part2s, part2q);
    final_kernel<<<256, 256, 0, stream>>>(a2, part2s, part2q, g2, bb2, feat, ow, ob,
                                          (float*)d_out);
}